// Round 1
// baseline (21.887 us; speedup 1.0000x reference)
//
#include <hip/hip_runtime.h>
#include <math.h>

#define NN 4096
#define ALPHA_C 1.0f
#define H_COUP_C 0.1f
#define DT_C 0.01f

__global__ void prep_uv(const float* __restrict__ x_old,
                        const float* __restrict__ y_old,
                        const float* __restrict__ b,
                        float2* __restrict__ uv) {
    int j = blockIdx.x * blockDim.x + threadIdx.x;
    if (j >= NN) return;
    const int half = NN / 2;
    float u, v;
    if (j < half) {
        u = x_old[2 * j];
        v = x_old[2 * j + 1];
    } else {
        int k = 2 * (j - half);
        u = y_old[k]     - b[k];
        v = y_old[k + 1] - b[k + 1];
    }
    uv[j] = make_float2(u, v);
}

__global__ __launch_bounds__(256) void cpg_row(
        const float* __restrict__ pd,
        const float2* __restrict__ uv,
        const float* __restrict__ x_old,
        const float* __restrict__ y_old,
        const float* __restrict__ x_old_dot,
        const float* __restrict__ omega,
        const float* __restrict__ A,
        const float* __restrict__ b,
        const float* __restrict__ h_a,
        const float* __restrict__ y_state,
        float* __restrict__ out) {
    const int i = blockIdx.x;
    const int tid = threadIdx.x;
    const float* row = pd + (size_t)i * NN;
    const float* uvf = reinterpret_cast<const float*>(uv);

    float acc = 0.0f;
    // 4096 elements / (256 threads * 4 per thread) = 4 float4 iterations
    #pragma unroll
    for (int k = 0; k < 4; ++k) {
        const int jb = (k * 256 + tid) * 4;
        float4 p4  = *reinterpret_cast<const float4*>(row + jb);
        float4 uva = *reinterpret_cast<const float4*>(uvf + 2 * jb);
        float4 uvb = *reinterpret_cast<const float4*>(uvf + 2 * jb + 4);
        float pv[4] = {p4.x, p4.y, p4.z, p4.w};
        float us[4] = {uva.x, uva.z, uvb.x, uvb.z};
        float vs[4] = {uva.y, uva.w, uvb.y, uvb.w};
        #pragma unroll
        for (int e = 0; e < 4; ++e) {
            int j = jb + e;
            float s, c;
            if (j == i) { s = 0.0f; c = 1.0f; }
            else        { s = __sinf(pv[e]); c = __cosf(pv[e]); }
            acc = fmaf(s, us[e], acc);
            acc = fmaf(c, vs[e], acc);
        }
    }

    // wave (64-lane) butterfly reduce
    #pragma unroll
    for (int off = 32; off > 0; off >>= 1)
        acc += __shfl_xor(acc, off, 64);

    __shared__ float wsum[4];
    const int wid = tid >> 6;
    if ((tid & 63) == 0) wsum[wid] = acc;
    __syncthreads();

    if (tid == 0) {
        float total = wsum[0] + wsum[1] + wsum[2] + wsum[3];
        float xo = x_old[i], yo = y_old[i], bi = b[i];
        float ym = yo - bi;
        float r_sq = xo * xo + ym * ym;
        float kd = ALPHA_C * (1.0f - r_sq);
        float zeta = 1.0f - h_a[i] * (xo / (fabsf(x_old_dot[i]) + 1e-9f));
        float wz = omega[i] / zeta;
        float2 uvi = uv[i];
        float dot = kd * uvi.y + wz * uvi.x + H_COUP_C * total;
        float m = 2.0f * omega[i];
        dot = fminf(fmaxf(dot, -m), m);
        float y_new = y_state[i] + (dot + bi) * DT_C;
        out[i] = A[i] * y_new;
    }
}

extern "C" void kernel_launch(void* const* d_in, const int* in_sizes, int n_in,
                              void* d_out, int out_size, void* d_ws, size_t ws_size,
                              hipStream_t stream) {
    const float* x_old     = (const float*)d_in[0];
    const float* y_old     = (const float*)d_in[1];
    const float* x_old_dot = (const float*)d_in[2];
    const float* omega     = (const float*)d_in[3];
    const float* A         = (const float*)d_in[4];
    const float* b         = (const float*)d_in[5];
    const float* h_a       = (const float*)d_in[6];
    const float* pd        = (const float*)d_in[7];
    const float* y_state   = (const float*)d_in[9];
    float* out = (float*)d_out;
    float2* uv = (float2*)d_ws;

    prep_uv<<<NN / 256, 256, 0, stream>>>(x_old, y_old, b, uv);
    cpg_row<<<NN, 256, 0, stream>>>(pd, uv, x_old, y_old, x_old_dot, omega,
                                    A, b, h_a, y_state, out);
}